// Round 10
// baseline (77.288 us; speedup 1.0000x reference)
//
#include <hip/hip_runtime.h>
#include <hip/hip_bf16.h>
#include <stdint.h>

#define B_ 4
#define M_ 4096
#define N_ 4096
#define D_ 256

typedef __attribute__((ext_vector_type(8))) short bf16x8;
typedef __attribute__((ext_vector_type(4))) float f32x4;

#define AS1 __attribute__((address_space(1)))
#define AS3 __attribute__((address_space(3)))

// RNE float->bf16 (no NaN in this data)
__device__ inline unsigned short f2bf(float f) {
    unsigned int u = __float_as_uint(f);
    return (unsigned short)((u + 0x7fffu + ((u >> 16) & 1u)) >> 16);
}

// One wave per row: compute 1/||row||, scale, convert to bf16.
__global__ __launch_bounds__(256) void norm_cvt(const float* __restrict__ x,
                                                const float* __restrict__ y,
                                                ushort* __restrict__ xb,
                                                ushort* __restrict__ yb) {
    int gw   = (blockIdx.x * 256 + threadIdx.x) >> 6;
    int lane = threadIdx.x & 63;
    const int R = B_ * 4096;
    const float* src;
    ushort* dst;
    if (gw < R) { src = x + (size_t)gw * D_;        dst = xb + (size_t)gw * D_; }
    else        { src = y + (size_t)(gw - R) * D_;  dst = yb + (size_t)(gw - R) * D_; }

    float4 v = reinterpret_cast<const float4*>(src)[lane];
    float ss = v.x * v.x + v.y * v.y + v.z * v.z + v.w * v.w;
#pragma unroll
    for (int off = 32; off; off >>= 1) ss += __shfl_xor(ss, off);
    float scale = ss > 0.f ? rsqrtf(ss) : 0.f;

    ushort4 o;
    o.x = f2bf(v.x * scale);
    o.y = f2bf(v.y * scale);
    o.z = f2bf(v.z * scale);
    o.w = f2bf(v.w * scale);
    reinterpret_cast<ushort4*>(dst)[lane] = o;
}

// C[b][m][n] = sum_d Yb[b][m][d] * Xb[b][n][d]
// Block: 128 rows x 4 col-tiles of 128 (quad), 4 waves 2x2 (wave = 64x64).
// BK=32, TRIPLE-buffered LDS (3 x [A 8K | B 8K] = 48 KB -> 2 blocks/CU),
// depth-2 stage prefetch, 8-store slices each K-step. Stores are decoupled
// from the load-gates: gates allow [stage(s+1), 2 slices, stage(s+2)] to
// remain in flight (in-order vmcnt), so they throttle to HBM pace instead
// of hard-draining store bursts. 32 K-steps.
__global__ __launch_bounds__(256, 2) void cosgemm(const ushort* __restrict__ Xb,
                                                  const ushort* __restrict__ Yb,
                                                  float* __restrict__ out) {
    __shared__ char smem[49152];   // 3 bufs x (A 8K + B 8K)

    const int tid  = threadIdx.x;
    const int w    = tid >> 6;
    const int lane = tid & 63;

    // XCD-aware bijective swizzle: 1024 blocks, 8 XCDs, 128 per XCD chunk
    int bid = blockIdx.x;
    int swz = ((bid & 7) << 7) | (bid >> 3);
    int b   = swz >> 8;             // batch (0..3)
    int t   = swz & 255;
    int tm  = (t >> 3) << 7;        // 32 row-tiles
    int tn0 = (t & 7) << 9;         // 8 quad-cols * 512

    const ushort* Ag = Yb + ((size_t)b * M_ + tm) * D_;
    const ushort* Bg = Xb + ((size_t)b * N_ + tn0) * D_;

    const int wr = (w >> 1) << 6;   // wave's 64-row block
    const int wc = (w & 1) << 6;    // wave's 64-col block

    // staging (BK=32): tile 128 rows x 64B; chunk = 16 rows (1KB), 8 chunks per
    // tile over 4 waves (2 each). LDS dest linear (lane -> row=l>>2, slot=l&3);
    // source slot pre-swizzled: LDS slot s of row r holds global slot
    // s ^ ((r>>1)&3)  [involution, verified conflict-free: full 8-perm / 2-way].
    const int srow  = lane >> 2;
    const int gslot = (lane & 3) ^ ((lane >> 3) & 3);

    // step s: quad ct = s>>3, k-chunk kc = s&7. Stage A and B tiles.
    auto stage = [&](int s) {
        char* base = smem + (s % 3) * 16384;
        const int kofs = (s & 7) * 32;
        const ushort* Bq = Bg + (size_t)((s >> 3) * 128) * D_ + kofs;
#pragma unroll
        for (int i = 0; i < 2; ++i) {
            int c = i * 4 + w;
            const ushort* ga = Ag + (size_t)(c * 16 + srow) * D_ + kofs + gslot * 8;
            __builtin_amdgcn_global_load_lds((const AS1 void*)ga,
                                             (AS3 void*)(base + c * 1024), 16, 0, 0);
            const ushort* gb = Bq + (size_t)(c * 16 + srow) * D_ + gslot * 8;
            __builtin_amdgcn_global_load_lds((const AS1 void*)gb,
                                             (AS3 void*)(base + 8192 + c * 1024), 16, 0, 0);
        }
    };

    // C/D layout: col = lane&15, row = (lane>>4)*4 + reg   [m89-verified]
    const int rj = (lane >> 4) << 2;
    const int cj = lane & 15;

    f32x4 acc0[4][4], acc1[4][4];

    // 8-store slice: quad pq, sub-slice t (m = t>>1, j-half = t&1)
    auto slice = [&](f32x4 (&acc)[4][4], int pq, int t) {
        const int m = t >> 1, jh = (t & 1) * 2;
        const int tn = tn0 + pq * 128;
#pragma unroll
        for (int jj = 0; jj < 2; ++jj) {
            size_t r = (size_t)(tm + wr + m * 16 + rj + jh + jj);
            float* rowp = out + ((size_t)b * M_ + r) * N_ + tn + wc + cj;
#pragma unroll
            for (int n = 0; n < 4; ++n)
                rowp[n * 16] = acc[m][n][jh + jj];
        }
    };

    stage(0);
    stage(1);

#pragma unroll
    for (int s = 0; s < 32; ++s) {
        const int ct = s >> 3, kc = s & 7, buf = s % 3;
        // barrier 1: buf[(s+2)%3]'s readers (step s-1) are done everywhere
        __builtin_amdgcn_s_barrier();
        if (s < 30) stage(s + 2);
        // gate: certify stage(s) retired. In-order vmcnt; exact count of ops
        // younger than stage(s) per the issue schedule (see ledger).
        if (s <= 8)       asm volatile("s_waitcnt vmcnt(8)"  ::: "memory");
        else if (s == 9)  asm volatile("s_waitcnt vmcnt(16)" ::: "memory");
        else if (s <= 29) asm volatile("s_waitcnt vmcnt(24)" ::: "memory");
        else if (s == 30) asm volatile("s_waitcnt vmcnt(20)" ::: "memory");
        else              asm volatile("s_waitcnt vmcnt(16)" ::: "memory");
        // barrier 2: all waves' chunks of buf[s] complete
        __builtin_amdgcn_s_barrier();
        __builtin_amdgcn_sched_barrier(0);

        const char* Abase = smem + buf * 16384;
        const char* Bbase = Abase + 8192;

        if (kc == 0) {
            if ((ct & 1) == 0) {
#pragma unroll
                for (int m = 0; m < 4; ++m)
#pragma unroll
                    for (int n = 0; n < 4; ++n)
                        acc0[m][n] = (f32x4){0.f, 0.f, 0.f, 0.f};
            } else {
#pragma unroll
                for (int m = 0; m < 4; ++m)
#pragma unroll
                    for (int n = 0; n < 4; ++n)
                        acc1[m][n] = (f32x4){0.f, 0.f, 0.f, 0.f};
            }
        }

        bf16x8 af[4], bfr[4];
#pragma unroll
        for (int m = 0; m < 4; ++m) {
            int row = wr + m * 16 + (lane & 15);
            int colb = (((lane >> 4) ^ ((row >> 1) & 3)) << 4);
            af[m] = *reinterpret_cast<const bf16x8*>(Abase + row * 64 + colb);
        }
#pragma unroll
        for (int n = 0; n < 4; ++n) {
            int row = wc + n * 16 + (lane & 15);
            int colb = (((lane >> 4) ^ ((row >> 1) & 3)) << 4);
            bfr[n] = *reinterpret_cast<const bf16x8*>(Bbase + row * 64 + colb);
        }
        if ((ct & 1) == 0) {
#pragma unroll
            for (int m = 0; m < 4; ++m)
#pragma unroll
                for (int n = 0; n < 4; ++n)
                    acc0[m][n] = __builtin_amdgcn_mfma_f32_16x16x32_bf16(
                        af[m], bfr[n], acc0[m][n], 0, 0, 0);
        } else {
#pragma unroll
            for (int m = 0; m < 4; ++m)
#pragma unroll
                for (int n = 0; n < 4; ++n)
                    acc1[m][n] = __builtin_amdgcn_mfma_f32_16x16x32_bf16(
                        af[m], bfr[n], acc1[m][n], 0, 0, 0);
        }

        // one 8-store slice of the PREVIOUS quad, every step (rate-matched)
        if (s >= 8) {
            const int pq = ct - 1 + ((kc == 0) ? 0 : 0);  // prev quad = (s-8)>>3
            const int qq = (s - 8) >> 3, tt = s & 7;
            __builtin_amdgcn_sched_barrier(0);
            if ((qq & 1) == 0) slice(acc0, qq, tt);
            else               slice(acc1, qq, tt);
            __builtin_amdgcn_sched_barrier(0);
            (void)pq;
        }
    }

    // tail: quad 3 (odd -> acc1)
#pragma unroll
    for (int t = 0; t < 8; ++t)
        slice(acc1, 3, t);
}

extern "C" void kernel_launch(void* const* d_in, const int* in_sizes, int n_in,
                              void* d_out, int out_size, void* d_ws, size_t ws_size,
                              hipStream_t stream) {
    const float* x = (const float*)d_in[0];   // [4,4096,256] f32
    const float* y = (const float*)d_in[1];   // [4,4096,256] f32
    float* out = (float*)d_out;               // [4,4096,4096] f32

    ushort* xb = (ushort*)d_ws;                       // bf16 normalized x
    ushort* yb = xb + (size_t)B_ * N_ * D_;           // bf16 normalized y

    norm_cvt<<<8192, 256, 0, stream>>>(x, y, xb, yb); // 32768 rows, 4 waves/block
    cosgemm<<<1024, 256, 0, stream>>>(xb, yb, out);   // 4 batches * 32 * 8 quad-tiles
}